// Round 10
// baseline (341.072 us; speedup 1.0000x reference)
//
#include <hip/hip_runtime.h>
#include <cstdint>

typedef unsigned short u16;
typedef __attribute__((ext_vector_type(4))) float f32x4;
typedef __attribute__((ext_vector_type(8))) short s16x8;
typedef __attribute__((ext_vector_type(2))) unsigned int u32x2;
typedef __attribute__((ext_vector_type(4))) unsigned int u32x4;
typedef __attribute__((ext_vector_type(4))) unsigned short u16x4;

#define MFMA16(a,b,c) __builtin_amdgcn_mfma_f32_16x16x32_bf16((a),(b),(c),0,0,0)

__device__ __forceinline__ u16 f2bf(float x) {
  unsigned u = __builtin_bit_cast(unsigned, x);
  unsigned r = (u + 0x7fffu + ((u >> 16) & 1u)) >> 16;   // RNE
  return (u16)r;
}
__device__ __forceinline__ unsigned cvt_pk_bf16(float lo, float hi) {
  unsigned r;
  asm volatile("v_cvt_pk_bf16_f32 %0, %1, %2" : "=v"(r) : "v"(lo), "v"(hi));
  return r;
}
// byte offset into a [rows][64]-u16 LDS tile, XOR-swizzled (G4 pattern)
__device__ __forceinline__ int swz(int row, int colb) {
  return (row * 128 + colb) ^ ((row & 7) << 4);
}
// async global->LDS, 16B/lane; LDS dest = wave-uniform base + lane*16
__device__ __forceinline__ void glds16(const u16* g, u16* l) {
  __builtin_amdgcn_global_load_lds(
      (const __attribute__((address_space(1))) void*)g,
      (__attribute__((address_space(3))) void*)l, 16, 0, 0);
}

// ---------------- fp32 -> bf16 convert (vectorized) ----------------
__global__ void cvt_f32_bf16(const float* __restrict__ in, u16* __restrict__ out, int n) {
  const int i = (blockIdx.x * 256 + threadIdx.x) * 4;
  if (i + 3 < n) {
    const float4 v = *(const float4*)(in + i);
    u32x2 o2;
    o2[0] = cvt_pk_bf16(v.x, v.y);
    o2[1] = cvt_pk_bf16(v.z, v.w);
    *(u32x2*)(out + i) = o2;
  }
}

// ---------------- quantum layer -> affine map A'(64x64), c(64) ----------------
// R = Kronecker product of 6 commuting 2x2 stage matrices M_i = [[c,-s],[s*cp,c*cp]].
__global__ __launch_bounds__(256) void build_quantum(
    const float* __restrict__ theta, const float* __restrict__ phi,
    const float* __restrict__ preW, const float* __restrict__ preb,
    const float* __restrict__ postW, const float* __restrict__ postb,
    float* __restrict__ Aout, float* __restrict__ cout_) {
  __shared__ float R[64][65];
  __shared__ float W[64][65];
  __shared__ float T[64][65];
  __shared__ float rbv[64];
  const int t = threadIdx.x;

  float m00[6], m01[6], m10[6], m11[6];
  #pragma unroll
  for (int i = 0; i < 6; ++i) {
    const float cth = cosf(theta[i]), sth = sinf(theta[i]), cph = cosf(phi[i]);
    m00[i] = cth; m01[i] = -sth; m10[i] = sth * cph; m11[i] = cth * cph;
  }
  for (int ii = t; ii < 4096; ii += 256) {
    const int r = ii >> 6, cc = ii & 63;
    float p = 1.f;
    #pragma unroll
    for (int i = 0; i < 6; ++i) {
      const int rb_ = (r >> i) & 1, cb = (cc >> i) & 1;
      p *= rb_ ? (cb ? m11[i] : m10[i]) : (cb ? m01[i] : m00[i]);
    }
    R[r][cc] = p;
    W[r][cc] = preW[ii];
  }
  __syncthreads();
  for (int ii = t; ii < 4096; ii += 256) {
    const int d = ii >> 6, j = ii & 63;
    float acc = 0.f;
    #pragma unroll
    for (int e = 0; e < 64; ++e) acc += R[d][e] * W[e][j];
    T[d][j] = acc;
  }
  if (t < 64) {
    float acc = 0.f;
    #pragma unroll
    for (int e = 0; e < 64; ++e) acc += R[t][e] * preb[e];
    rbv[t] = acc;
  }
  __syncthreads();
  for (int ii = t; ii < 4096; ii += 256) W[ii >> 6][ii & 63] = postW[ii];
  __syncthreads();
  for (int ii = t; ii < 4096; ii += 256) {
    const int d = ii >> 6, j = ii & 63;
    float acc = (d == j) ? 1.f : 0.f;
    #pragma unroll
    for (int e = 0; e < 64; ++e) acc += W[d][e] * T[e][j];
    Aout[ii] = acc;
  }
  if (t < 64) {
    float acc = postb[t];
    #pragma unroll
    for (int e = 0; e < 64; ++e) acc += W[t][e] * rbv[e];
    cout_[t] = acc;
  }
}

// ---------------- fold A' into projection weight (per head, block-diag) ----------------
__global__ __launch_bounds__(256) void fold_weight(
    const float* __restrict__ Ap, const float* __restrict__ cvec,
    const float* __restrict__ W, const float* __restrict__ bin,
    u16* __restrict__ Wout, float* __restrict__ bout, float scale) {
  __shared__ float sW[64][64];
  __shared__ float sA[64][64];
  const int h = blockIdx.y, k0 = blockIdx.x * 64;
  const int t = threadIdx.x;
  for (int ii = t; ii < 4096; ii += 256) {
    const int e = ii >> 6, kk = ii & 63;
    sW[e][kk] = W[(size_t)(h * 64 + e) * 1024 + k0 + kk];
    sA[e][kk] = Ap[ii];
  }
  __syncthreads();
  for (int ii = t; ii < 4096; ii += 256) {
    const int d = ii >> 6, kk = ii & 63;
    float acc = 0.f;
    #pragma unroll
    for (int e = 0; e < 64; ++e) acc += sA[d][e] * sW[e][kk];
    Wout[(size_t)(h * 64 + d) * 1024 + k0 + kk] = f2bf(acc * scale);
  }
  if (blockIdx.x == 0 && t < 64) {
    const int d = t;
    float acc = cvec[d];
    for (int e = 0; e < 64; ++e) acc += sA[d][e] * bin[h * 64 + e];
    bout[h * 64 + d] = acc * scale;
  }
}

// ---------------- bf16 GEMM, C[m,n] = sum_k A[m,k]*B[n,k] + bias[n] ----------------
// 128x128 tile, BK=64. Both A and B staged via global_load_lds w16, double-buffered,
// XOR-swizzled (pre-swizzled source + swizzled read — G21 both-sides).
// MODE 0: bf16 out (B,H,S,64); 1: f32 flat; 2: bf16 V^T (B,H,64,S)
template<int MODE>
__global__ __launch_bounds__(256, 2) void gemm_rs(
    const u16* __restrict__ Ab, const u16* __restrict__ Bw,
    const float* __restrict__ bias, u16* __restrict__ outB,
    float* __restrict__ outF, int M, int N, int K) {
  __shared__ u16 As[2][8192];                  // [2][128][64] glds, swizzled
  __shared__ u16 Bs[2][8192];
  const int t = threadIdx.x;
  const int l = t & 63, w = t >> 6;
  const int g = l >> 4, c = l & 15;
  const int wr = w >> 1, wc = w & 1;
  const int m0 = blockIdx.x * 128, n0 = blockIdx.y * 128;

  const int lrow8 = l >> 3;                    // 0..7 (row within 8-row group)
  const int gcolsw = ((l & 7) ^ lrow8) * 8;    // pre-swizzled source k-offset (elems)
  const int lbase = w * 512;                   // u16 LDS base per wave per call-block

  // stage a [128][64] bf16 tile into ldsbuf (linear dest, inverse-swizzled source)
  auto glds_tile = [&](const u16* src, u16* ldsbuf, int rbase, int kk) {
    #pragma unroll
    for (int i = 0; i < 4; ++i) {
      const int grow = i * 32 + w * 8 + lrow8;
      glds16(src + (size_t)(rbase + grow) * K + kk + gcolsw, ldsbuf + i * 2048 + lbase);
    }
  };

  f32x4 acc[4][4];
  #pragma unroll
  for (int i = 0; i < 4; ++i)
    #pragma unroll
    for (int j = 0; j < 4; ++j) acc[i][j] = f32x4{0.f, 0.f, 0.f, 0.f};

  // prologue
  glds_tile(Ab, As[0], m0, 0);
  glds_tile(Bw, Bs[0], n0, 0);

  int cur = 0;
  for (int kk = 0; kk < K; kk += 64) {
    __syncthreads();                      // glds(kk) drained, tiles visible
    const int nk = kk + 64;
    if (nk < K) {                         // prefetch next tile (overlaps MFMA)
      glds_tile(Ab, As[cur ^ 1], m0, nk);
      glds_tile(Bw, Bs[cur ^ 1], n0, nk);
    }

    s16x8 af[4][2], bfr[4][2];
    {
      const char* Ab2 = (const char*)As[cur];
      #pragma unroll
      for (int mi = 0; mi < 4; ++mi) {
        const int ar = wr * 64 + mi * 16 + c;
        #pragma unroll
        for (int kt = 0; kt < 2; ++kt)
          af[mi][kt] = *(const s16x8*)(Ab2 + ar * 128 + (((kt * 4 + g) ^ (c & 7)) << 4));
      }
      const char* Bb = (const char*)Bs[cur];
      #pragma unroll
      for (int ni = 0; ni < 4; ++ni) {
        const int rr = wc * 64 + ni * 16 + c;
        #pragma unroll
        for (int kt = 0; kt < 2; ++kt)
          bfr[ni][kt] = *(const s16x8*)(Bb + rr * 128 + (((kt * 4 + g) ^ (c & 7)) << 4));
      }
    }
    #pragma unroll
    for (int kt = 0; kt < 2; ++kt)
      #pragma unroll
      for (int mi = 0; mi < 4; ++mi)
        #pragma unroll
        for (int ni = 0; ni < 4; ++ni)
          acc[mi][ni] = MFMA16(af[mi][kt], bfr[ni][kt], acc[mi][ni]);
    __syncthreads();
    cur ^= 1;
  }

  #pragma unroll
  for (int ni = 0; ni < 4; ++ni) {
    const int n = n0 + wc * 64 + ni * 16 + c;
    const float bb = bias[n];
    #pragma unroll
    for (int mi = 0; mi < 4; ++mi) {
      const int mb = m0 + wr * 64 + mi * 16 + g * 4;
      if (MODE == 2) {
        const int b = mb >> 11, sb = mb & 2047, h = n >> 6, d = n & 63;
        u16x4 pk;
        #pragma unroll
        for (int r = 0; r < 4; ++r) pk[r] = f2bf(acc[mi][ni][r] + bb);
        *(u16x4*)(outB + ((size_t)(b * 16 + h) * 64 + d) * 2048 + sb) = pk;
      } else {
        #pragma unroll
        for (int r = 0; r < 4; ++r) {
          const float val = acc[mi][ni][r] + bb;
          const int m = mb + r;
          if (MODE == 0) {
            const int b = m >> 11, s = m & 2047, h = n >> 6, d = n & 63;
            outB[((size_t)((b * 16 + h) * 2048 + s)) * 64 + d] = f2bf(val);
          } else {
            outF[(size_t)m * N + n] = val;
          }
        }
      }
    }
  }
}

// ---------------- flash attention, D=64, swapped QK^T (S^T), O^T = V^T * P^T ----------------
// (r8 config — best known) K/V^T staged to XOR-swizzled LDS with reg-prefetch;
// XCD-swizzled 1-D grid; per-wave P, single lgkm drain; defer-max; exp2 domain.
__global__ __launch_bounds__(256, 2) void attn_fwd(
    const u16* __restrict__ Qg, const u16* __restrict__ Kg,
    const u16* __restrict__ Vtg, u16* __restrict__ Og) {
  __shared__ u16 Ks[64 * 64];
  __shared__ u16 Vs[64 * 64];
  __shared__ u16 Ps[4][32 * 64];
  const int t = threadIdx.x;
  const int l = t & 63, w = t >> 6;
  const int g = l >> 4, c = l & 15;
  const int bid = blockIdx.x;
  const int xcd = bid & 7, kk_ = bid >> 3;
  const int bh = ((kk_ >> 4) << 3) + xcd;   // 0..63
  const int qx = kk_ & 15;                  // 0..15
  const size_t base = (size_t)bh * (2048 * 64);
  const int q0 = qx * 128 + w * 32;

  s16x8 qf[2][2];
  #pragma unroll
  for (int nt = 0; nt < 2; ++nt)
    #pragma unroll
    for (int kt = 0; kt < 2; ++kt)
      qf[nt][kt] = *(const s16x8*)(Qg + base + (size_t)(q0 + nt * 16 + c) * 64 + kt * 32 + g * 8);

  float mS[2] = {-1e30f, -1e30f};
  float lP[2] = {0.f, 0.f};                 // per-lane partial row-sum
  f32x4 o[4][2];
  #pragma unroll
  for (int i = 0; i < 4; ++i) { o[i][0] = f32x4{0.f,0.f,0.f,0.f}; o[i][1] = f32x4{0.f,0.f,0.f,0.f}; }

  const int row1 = t >> 3, ch1 = t & 7;
  char* Pw = (char*)&Ps[w][0];
  char* Kb = (char*)Ks;
  char* Vb = (char*)Vs;

  // prologue: load tile 0 K and V^T into regs
  s16x8 kreg[2], vreg[2];
  #pragma unroll
  for (int j = 0; j < 2; ++j) {
    const int row = row1 + 32 * j;
    kreg[j] = *(const s16x8*)(Kg + base + (size_t)row * 64 + ch1 * 8);
    vreg[j] = *(const s16x8*)(Vtg + base + (size_t)row * 2048 + ch1 * 8);
  }

  for (int it = 0; it < 32; ++it) {
    const int kv0 = it * 64;
    #pragma unroll
    for (int j = 0; j < 2; ++j) {
      const int row = row1 + 32 * j;
      *(s16x8*)(Kb + swz(row, ch1 * 16)) = kreg[j];
      *(s16x8*)(Vb + swz(row, ch1 * 16)) = vreg[j];
    }
    __syncthreads();
    if (it != 31) {
      const int kv0n = kv0 + 64;
      #pragma unroll
      for (int j = 0; j < 2; ++j) {
        const int row = row1 + 32 * j;
        kreg[j] = *(const s16x8*)(Kg + base + (size_t)(kv0n + row) * 64 + ch1 * 8);
        vreg[j] = *(const s16x8*)(Vtg + base + (size_t)row * 2048 + kv0n + ch1 * 8);
      }
    }

    // ---- S^T = K * Q^T ----
    f32x4 st[4][2];
    __builtin_amdgcn_s_setprio(1);
    #pragma unroll
    for (int mt = 0; mt < 4; ++mt) {
      const int kr = mt * 16 + c;
      const s16x8 k0 = *(const s16x8*)(Kb + swz(kr, g * 16));
      const s16x8 k1 = *(const s16x8*)(Kb + swz(kr, 64 + g * 16));
      #pragma unroll
      for (int nt = 0; nt < 2; ++nt) {
        f32x4 z = {0.f, 0.f, 0.f, 0.f};
        z = MFMA16(k0, qf[nt][0], z);
        z = MFMA16(k1, qf[nt][1], z);
        st[mt][nt] = z;
      }
    }
    __builtin_amdgcn_s_setprio(0);

    // ---- online softmax (exp2 domain, defer-max, per-lane partial l) + P writes ----
    #pragma unroll
    for (int nt = 0; nt < 2; ++nt) {
      float tmax = st[0][nt][0];
      #pragma unroll
      for (int mt = 0; mt < 4; ++mt)
        #pragma unroll
        for (int r = 0; r < 4; ++r) tmax = fmaxf(tmax, st[mt][nt][r]);
      tmax = fmaxf(tmax, __shfl_xor(tmax, 16));
      tmax = fmaxf(tmax, __shfl_xor(tmax, 32));
      if (__any(tmax - mS[nt] > 8.f)) {            // T13: rescale only when needed
        const float mnew = fmaxf(mS[nt], tmax);
        const float alpha = exp2f(mS[nt] - mnew);
        lP[nt] *= alpha;
        #pragma unroll
        for (int dt = 0; dt < 4; ++dt) o[dt][nt] *= alpha;
        mS[nt] = mnew;
      }
      float psum = 0.f;
      #pragma unroll
      for (int mt = 0; mt < 4; ++mt)
        #pragma unroll
        for (int r = 0; r < 4; ++r) {
          const float p = exp2f(st[mt][nt][r] - mS[nt]);
          st[mt][nt][r] = p;
          psum += p;
        }
      lP[nt] += psum;

      const int q32 = nt * 16 + c;
      #pragma unroll
      for (int mt = 0; mt < 4; ++mt) {
        u32x2 pv;
        pv[0] = cvt_pk_bf16(st[mt][nt][0], st[mt][nt][1]);
        pv[1] = cvt_pk_bf16(st[mt][nt][2], st[mt][nt][3]);
        *(u32x2*)(Pw + swz(q32, mt * 32 + g * 8)) = pv;
      }
    }
    asm volatile("s_waitcnt lgkmcnt(0)" ::: "memory");   // same-wave LDS RAW (both nt)

    // ---- PV: O^T += V^T * P^T (V fragment read once, shared across nt) ----
    __builtin_amdgcn_s_setprio(1);
    #pragma unroll
    for (int kkb = 0; kkb < 2; ++kkb) {
      const s16x8 pb0 = *(const s16x8*)(Pw + swz(c,      kkb * 64 + g * 16));
      const s16x8 pb1 = *(const s16x8*)(Pw + swz(16 + c, kkb * 64 + g * 16));
      #pragma unroll
      for (int dt = 0; dt < 4; ++dt) {
        const s16x8 vfr = *(const s16x8*)(Vb + swz(dt * 16 + c, kkb * 64 + g * 16));
        o[dt][0] = MFMA16(vfr, pb0, o[dt][0]);
        o[dt][1] = MFMA16(vfr, pb1, o[dt][1]);
      }
    }
    __builtin_amdgcn_s_setprio(0);
    __syncthreads();
  }

  // ---- epilogue: reduce l across g, then O^T/l -> attn_out bf16 (B,S,E) ----
  const int b = bh >> 4, h = bh & 15;
  #pragma unroll
  for (int nt = 0; nt < 2; ++nt) {
    float lS = lP[nt];
    lS += __shfl_xor(lS, 16);
    lS += __shfl_xor(lS, 32);
    const float inv = 1.0f / lS;
    const int token = q0 + nt * 16 + c;
    u16* orow = Og + ((size_t)(b * 2048 + token)) * 1024 + h * 64;
    #pragma unroll
    for (int dt = 0; dt < 4; ++dt) {
      u32x2 pv;
      pv[0] = cvt_pk_bf16(o[dt][nt][0] * inv, o[dt][nt][1] * inv);
      pv[1] = cvt_pk_bf16(o[dt][nt][2] * inv, o[dt][nt][3] * inv);
      *(u32x2*)(orow + dt * 16 + g * 4) = pv;
    }
  }
}

// ---------------- launcher ----------------
extern "C" void kernel_launch(void* const* d_in, const int* in_sizes, int n_in,
                              void* d_out, int out_size, void* d_ws, size_t ws_size,
                              hipStream_t stream) {
  (void)in_sizes; (void)n_in; (void)out_size; (void)ws_size;
  const float* query   = (const float*)d_in[0];
  const float* key     = (const float*)d_in[1];
  const float* value   = (const float*)d_in[2];
  const float* wq      = (const float*)d_in[3];
  const float* bq      = (const float*)d_in[4];
  const float* wk      = (const float*)d_in[5];
  const float* bk      = (const float*)d_in[6];
  const float* wv      = (const float*)d_in[7];
  const float* bv      = (const float*)d_in[8];
  const float* wo      = (const float*)d_in[9];
  const float* bo      = (const float*)d_in[10];
  const float* q_theta = (const float*)d_in[11];
  const float* q_phi   = (const float*)d_in[12];
  const float* q_preW  = (const float*)d_in[13];
  const float* q_preb  = (const float*)d_in[14];
  const float* q_postW = (const float*)d_in[15];
  const float* q_postb = (const float*)d_in[16];
  const float* k_theta = (const float*)d_in[17];
  const float* k_phi   = (const float*)d_in[18];
  const float* k_preW  = (const float*)d_in[19];
  const float* k_preb  = (const float*)d_in[20];
  const float* k_postW = (const float*)d_in[21];
  const float* k_postb = (const float*)d_in[22];

  char* ws = (char*)d_ws;
  const size_t ACT = (size_t)8192 * 1024 * 2;   // one bf16 activation tensor (16 MB)
  u16* qbf = (u16*)(ws + 0 * ACT);              // bf16 copies of inputs
  u16* kbf = (u16*)(ws + 1 * ACT);
  u16* vbf = (u16*)(ws + 2 * ACT);
  u16* Qt  = (u16*)(ws + 3 * ACT);              // (B,H,S,64) bf16
  u16* Kt  = (u16*)(ws + 4 * ACT);              // (B,H,S,64) bf16
  u16* VtT = (u16*)(ws + 5 * ACT);              // (B,H,64,S) bf16  == V^T per (b,h)
  u16* AO  = (u16*)(ws + 6 * ACT);              // attn out, (B,S,E) bf16
  char* wb = ws + 7 * ACT;
  const size_t WSZ = (size_t)1024 * 1024 * 2;
  u16* Wqp = (u16*)(wb);
  u16* Wkp = (u16*)(wb + WSZ);
  u16* Wvb = (u16*)(wb + 2 * WSZ);
  u16* Wob = (u16*)(wb + 3 * WSZ);
  float* bqp = (float*)(wb + 4 * WSZ);
  float* bkp = (float*)(wb + 4 * WSZ + 4096);
  float* Aq  = (float*)(wb + 4 * WSZ + 8192);
  float* Ak  = (float*)(wb + 4 * WSZ + 8192 + 16384);
  float* cq  = (float*)(wb + 4 * WSZ + 8192 + 32768);
  float* ck  = (float*)(wb + 4 * WSZ + 8192 + 32768 + 256);

  // bf16 conversions (memory-bound, off the GEMM critical path)
  cvt_f32_bf16<<<8192, 256, 0, stream>>>(query, qbf, 8388608);
  cvt_f32_bf16<<<8192, 256, 0, stream>>>(key,   kbf, 8388608);
  cvt_f32_bf16<<<8192, 256, 0, stream>>>(value, vbf, 8388608);
  cvt_f32_bf16<<<1024, 256, 0, stream>>>(wv, Wvb, 1048576);
  cvt_f32_bf16<<<1024, 256, 0, stream>>>(wo, Wob, 1048576);
  build_quantum<<<1, 256, 0, stream>>>(q_theta, q_phi, q_preW, q_preb, q_postW, q_postb, Aq, cq);
  build_quantum<<<1, 256, 0, stream>>>(k_theta, k_phi, k_preW, k_preb, k_postW, k_postb, Ak, ck);
  // Q scale = 1/sqrt(64) * log2(e): scores emerge in exp2 domain
  fold_weight<<<dim3(16, 16), 256, 0, stream>>>(Aq, cq, wq, bq, Wqp, bqp, 0.18033688f);
  fold_weight<<<dim3(16, 16), 256, 0, stream>>>(Ak, ck, wk, bk, Wkp, bkp, 1.0f);

  gemm_rs<0><<<dim3(64, 8), 256, 0, stream>>>(qbf, Wqp, bqp, Qt,  nullptr, 8192, 1024, 1024);
  gemm_rs<0><<<dim3(64, 8), 256, 0, stream>>>(kbf, Wkp, bkp, Kt,  nullptr, 8192, 1024, 1024);
  gemm_rs<2><<<dim3(64, 8), 256, 0, stream>>>(vbf, Wvb, bv,  VtT, nullptr, 8192, 1024, 1024);

  attn_fwd<<<1024, 256, 0, stream>>>(Qt, Kt, VtT, AO);

  gemm_rs<1><<<dim3(64, 8), 256, 0, stream>>>(AO, Wob, bo, nullptr, (float*)d_out, 8192, 1024, 1024);
}

// Round 11
// 299.160 us; speedup vs baseline: 1.1401x; 1.1401x over previous
//
#include <hip/hip_runtime.h>
#include <cstdint>

typedef unsigned short u16;
typedef __attribute__((ext_vector_type(4))) float f32x4;
typedef __attribute__((ext_vector_type(8))) short s16x8;
typedef __attribute__((ext_vector_type(2))) unsigned int u32x2;
typedef __attribute__((ext_vector_type(4))) unsigned int u32x4;
typedef __attribute__((ext_vector_type(4))) unsigned short u16x4;

#define MFMA16(a,b,c) __builtin_amdgcn_mfma_f32_16x16x32_bf16((a),(b),(c),0,0,0)

__device__ __forceinline__ u16 f2bf(float x) {
  unsigned u = __builtin_bit_cast(unsigned, x);
  unsigned r = (u + 0x7fffu + ((u >> 16) & 1u)) >> 16;   // RNE
  return (u16)r;
}
__device__ __forceinline__ unsigned cvt_pk_bf16(float lo, float hi) {
  unsigned r;
  asm volatile("v_cvt_pk_bf16_f32 %0, %1, %2" : "=v"(r) : "v"(lo), "v"(hi));
  return r;
}
// byte offset into a [rows][64]-u16 LDS tile, XOR-swizzled (G4 pattern)
__device__ __forceinline__ int swz(int row, int colb) {
  return (row * 128 + colb) ^ ((row & 7) << 4);
}
// async global->LDS, 16B/lane; LDS dest = wave-uniform base + lane*16
__device__ __forceinline__ void glds16(const u16* g, u16* l) {
  __builtin_amdgcn_global_load_lds(
      (const __attribute__((address_space(1))) void*)g,
      (__attribute__((address_space(3))) void*)l, 16, 0, 0);
}

// ---------------- fp32 -> bf16 convert (weights only) ----------------
__global__ void cvt_f32_bf16(const float* __restrict__ in, u16* __restrict__ out, int n) {
  const int i = (blockIdx.x * 256 + threadIdx.x) * 4;
  if (i + 3 < n) {
    const float4 v = *(const float4*)(in + i);
    u32x2 o2;
    o2[0] = cvt_pk_bf16(v.x, v.y);
    o2[1] = cvt_pk_bf16(v.z, v.w);
    *(u32x2*)(out + i) = o2;
  }
}

// ---------------- quantum layer -> affine map A'(64x64), c(64) ----------------
// R = Kronecker product of 6 commuting 2x2 stage matrices M_i = [[c,-s],[s*cp,c*cp]].
__global__ __launch_bounds__(256) void build_quantum(
    const float* __restrict__ theta, const float* __restrict__ phi,
    const float* __restrict__ preW, const float* __restrict__ preb,
    const float* __restrict__ postW, const float* __restrict__ postb,
    float* __restrict__ Aout, float* __restrict__ cout_) {
  __shared__ float R[64][65];
  __shared__ float W[64][65];
  __shared__ float T[64][65];
  __shared__ float rbv[64];
  const int t = threadIdx.x;

  float m00[6], m01[6], m10[6], m11[6];
  #pragma unroll
  for (int i = 0; i < 6; ++i) {
    const float cth = cosf(theta[i]), sth = sinf(theta[i]), cph = cosf(phi[i]);
    m00[i] = cth; m01[i] = -sth; m10[i] = sth * cph; m11[i] = cth * cph;
  }
  for (int ii = t; ii < 4096; ii += 256) {
    const int r = ii >> 6, cc = ii & 63;
    float p = 1.f;
    #pragma unroll
    for (int i = 0; i < 6; ++i) {
      const int rb_ = (r >> i) & 1, cb = (cc >> i) & 1;
      p *= rb_ ? (cb ? m11[i] : m10[i]) : (cb ? m01[i] : m00[i]);
    }
    R[r][cc] = p;
    W[r][cc] = preW[ii];
  }
  __syncthreads();
  for (int ii = t; ii < 4096; ii += 256) {
    const int d = ii >> 6, j = ii & 63;
    float acc = 0.f;
    #pragma unroll
    for (int e = 0; e < 64; ++e) acc += R[d][e] * W[e][j];
    T[d][j] = acc;
  }
  if (t < 64) {
    float acc = 0.f;
    #pragma unroll
    for (int e = 0; e < 64; ++e) acc += R[t][e] * preb[e];
    rbv[t] = acc;
  }
  __syncthreads();
  for (int ii = t; ii < 4096; ii += 256) W[ii >> 6][ii & 63] = postW[ii];
  __syncthreads();
  for (int ii = t; ii < 4096; ii += 256) {
    const int d = ii >> 6, j = ii & 63;
    float acc = (d == j) ? 1.f : 0.f;
    #pragma unroll
    for (int e = 0; e < 64; ++e) acc += W[d][e] * T[e][j];
    Aout[ii] = acc;
  }
  if (t < 64) {
    float acc = postb[t];
    #pragma unroll
    for (int e = 0; e < 64; ++e) acc += W[t][e] * rbv[e];
    cout_[t] = acc;
  }
}

// ---------------- fold A' into projection weight (per head, block-diag) ----------------
__global__ __launch_bounds__(256) void fold_weight(
    const float* __restrict__ Ap, const float* __restrict__ cvec,
    const float* __restrict__ W, const float* __restrict__ bin,
    u16* __restrict__ Wout, float* __restrict__ bout, float scale) {
  __shared__ float sW[64][64];
  __shared__ float sA[64][64];
  const int h = blockIdx.y, k0 = blockIdx.x * 64;
  const int t = threadIdx.x;
  for (int ii = t; ii < 4096; ii += 256) {
    const int e = ii >> 6, kk = ii & 63;
    sW[e][kk] = W[(size_t)(h * 64 + e) * 1024 + k0 + kk];
    sA[e][kk] = Ap[ii];
  }
  __syncthreads();
  for (int ii = t; ii < 4096; ii += 256) {
    const int d = ii >> 6, kk = ii & 63;
    float acc = 0.f;
    #pragma unroll
    for (int e = 0; e < 64; ++e) acc += sA[d][e] * sW[e][kk];
    Wout[(size_t)(h * 64 + d) * 1024 + k0 + kk] = f2bf(acc * scale);
  }
  if (blockIdx.x == 0 && t < 64) {
    const int d = t;
    float acc = cvec[d];
    for (int e = 0; e < 64; ++e) acc += sA[d][e] * bin[h * 64 + e];
    bout[h * 64 + d] = acc * scale;
  }
}

// ---------------- bf16 GEMM, C[m,n] = sum_k A[m,k]*B[n,k] + bias[n] ----------------
// (r8 config — best known) 128x128 tile, BK=64. B via global_load_lds w16, double-buffered,
// XOR-swizzled (G21 both-sides). A: f32 reg-staged+cvt (AF32) or glds (bf16).
// MODE 0: bf16 out (B,H,S,64); 1: f32 flat; 2: bf16 V^T (B,H,64,S)
template<int AF32, int MODE>
__global__ __launch_bounds__(256, 2) void gemm_rs(
    const void* __restrict__ Asrc, const u16* __restrict__ Bw,
    const float* __restrict__ bias, u16* __restrict__ outB,
    float* __restrict__ outF, int M, int N, int K) {
  __shared__ u16 AsBuf[AF32 ? 9216 : 16384];   // AF32: [128][72]; else: [2][128][64] glds
  __shared__ u16 Bs[2][8192];                  // [2][128][64] glds, swizzled
  const int t = threadIdx.x;
  const int l = t & 63, w = t >> 6;
  const int g = l >> 4, c = l & 15;
  const int wr = w >> 1, wc = w & 1;
  const int m0 = blockIdx.x * 128, n0 = blockIdx.y * 128;

  const int lrow8 = l >> 3;                    // 0..7 (row within 8-row group)
  const int gcolsw = ((l & 7) ^ lrow8) * 8;    // pre-swizzled source k-offset (elems)
  const int lbase = w * 512;                   // u16 LDS base per wave per call-block

  // stage a [128][64] bf16 tile into ldsbuf (linear dest, inverse-swizzled source)
  auto glds_tile = [&](const u16* src, u16* ldsbuf, int rbase, int kk) {
    #pragma unroll
    for (int i = 0; i < 4; ++i) {
      const int grow = i * 32 + w * 8 + lrow8;
      glds16(src + (size_t)(rbase + grow) * K + kk + gcolsw, ldsbuf + i * 2048 + lbase);
    }
  };

  const int rowA32 = t >> 3, colA32 = (t & 7) * 8;   // AF32 staging geometry
  float4 fa[4][2];
  auto issue_A = [&](int kk) {
    const float* Af = (const float*)Asrc;
    #pragma unroll
    for (int i2 = 0; i2 < 4; ++i2) {
      const float* p = Af + (size_t)(m0 + rowA32 + i2 * 32) * K + kk + colA32;
      fa[i2][0] = *(const float4*)p;
      fa[i2][1] = *(const float4*)(p + 4);
    }
  };

  f32x4 acc[4][4];
  #pragma unroll
  for (int i = 0; i < 4; ++i)
    #pragma unroll
    for (int j = 0; j < 4; ++j) acc[i][j] = f32x4{0.f, 0.f, 0.f, 0.f};

  // prologue
  if constexpr (AF32) issue_A(0);
  else glds_tile((const u16*)Asrc, AsBuf, m0, 0);
  glds_tile(Bw, Bs[0], n0, 0);

  int cur = 0;
  for (int kk = 0; kk < K; kk += 64) {
    if constexpr (AF32) {
      #pragma unroll
      for (int i2 = 0; i2 < 4; ++i2) {
        u32x4 o4;
        o4[0] = cvt_pk_bf16(fa[i2][0].x, fa[i2][0].y);
        o4[1] = cvt_pk_bf16(fa[i2][0].z, fa[i2][0].w);
        o4[2] = cvt_pk_bf16(fa[i2][1].x, fa[i2][1].y);
        o4[3] = cvt_pk_bf16(fa[i2][1].z, fa[i2][1].w);
        *(u32x4*)&AsBuf[(rowA32 + i2 * 32) * 72 + colA32] = o4;
      }
    }
    __syncthreads();                      // A visible; glds(kk) drained
    const int nk = kk + 64;
    if (nk < K) {                         // prefetch next tile (overlaps MFMA)
      glds_tile(Bw, Bs[cur ^ 1], n0, nk);
      if constexpr (AF32) issue_A(nk);
      else glds_tile((const u16*)Asrc, AsBuf + (cur ^ 1) * 8192, m0, nk);
    }

    s16x8 af[4][2], bfr[4][2];
    if constexpr (AF32) {
      #pragma unroll
      for (int mi = 0; mi < 4; ++mi)
        #pragma unroll
        for (int kt = 0; kt < 2; ++kt)
          af[mi][kt] = *(const s16x8*)&AsBuf[(wr * 64 + mi * 16 + c) * 72 + kt * 32 + g * 8];
    } else {
      const char* Ab2 = (const char*)(AsBuf + cur * 8192);
      #pragma unroll
      for (int mi = 0; mi < 4; ++mi) {
        const int ar = wr * 64 + mi * 16 + c;
        #pragma unroll
        for (int kt = 0; kt < 2; ++kt)
          af[mi][kt] = *(const s16x8*)(Ab2 + ar * 128 + (((kt * 4 + g) ^ (c & 7)) << 4));
      }
    }
    {
      const char* Bb = (const char*)Bs[cur];
      #pragma unroll
      for (int ni = 0; ni < 4; ++ni) {
        const int rr = wc * 64 + ni * 16 + c;
        #pragma unroll
        for (int kt = 0; kt < 2; ++kt)
          bfr[ni][kt] = *(const s16x8*)(Bb + rr * 128 + (((kt * 4 + g) ^ (c & 7)) << 4));
      }
    }
    #pragma unroll
    for (int kt = 0; kt < 2; ++kt)
      #pragma unroll
      for (int mi = 0; mi < 4; ++mi)
        #pragma unroll
        for (int ni = 0; ni < 4; ++ni)
          acc[mi][ni] = MFMA16(af[mi][kt], bfr[ni][kt], acc[mi][ni]);
    __syncthreads();
    cur ^= 1;
  }

  #pragma unroll
  for (int ni = 0; ni < 4; ++ni) {
    const int n = n0 + wc * 64 + ni * 16 + c;
    const float bb = bias[n];
    #pragma unroll
    for (int mi = 0; mi < 4; ++mi) {
      const int mb = m0 + wr * 64 + mi * 16 + g * 4;
      if (MODE == 2) {
        const int b = mb >> 11, sb = mb & 2047, h = n >> 6, d = n & 63;
        u16x4 pk;
        #pragma unroll
        for (int r = 0; r < 4; ++r) pk[r] = f2bf(acc[mi][ni][r] + bb);
        *(u16x4*)(outB + ((size_t)(b * 16 + h) * 64 + d) * 2048 + sb) = pk;
      } else {
        #pragma unroll
        for (int r = 0; r < 4; ++r) {
          const float val = acc[mi][ni][r] + bb;
          const int m = mb + r;
          if (MODE == 0) {
            const int b = m >> 11, s = m & 2047, h = n >> 6, d = n & 63;
            outB[((size_t)((b * 16 + h) * 2048 + s)) * 64 + d] = f2bf(val);
          } else {
            outF[(size_t)m * N + n] = val;
          }
        }
      }
    }
  }
}

// ---------------- flash attention, D=64, swapped QK^T (S^T), O^T = V^T * P^T ----------------
// NO online max: scores in exp2 domain are range-safe (|score|*log2e/8 << 127), and
// max-subtraction cancels in O/l. P = exp2(S) directly; l accumulated by MFMA with a
// ones A-fragment (row-sum of P). K/V^T staged to XOR-swizzled LDS with reg-prefetch;
// XCD-swizzled 1-D grid; per-wave P, single lgkm drain.
__global__ __launch_bounds__(256, 2) void attn_fwd(
    const u16* __restrict__ Qg, const u16* __restrict__ Kg,
    const u16* __restrict__ Vtg, u16* __restrict__ Og) {
  __shared__ u16 Ks[64 * 64];
  __shared__ u16 Vs[64 * 64];
  __shared__ u16 Ps[4][32 * 64];
  const int t = threadIdx.x;
  const int l = t & 63, w = t >> 6;
  const int g = l >> 4, c = l & 15;
  const int bid = blockIdx.x;
  const int xcd = bid & 7, kk_ = bid >> 3;
  const int bh = ((kk_ >> 4) << 3) + xcd;   // 0..63
  const int qx = kk_ & 15;                  // 0..15
  const size_t base = (size_t)bh * (2048 * 64);
  const int q0 = qx * 128 + w * 32;

  s16x8 qf[2][2];
  #pragma unroll
  for (int nt = 0; nt < 2; ++nt)
    #pragma unroll
    for (int kt = 0; kt < 2; ++kt)
      qf[nt][kt] = *(const s16x8*)(Qg + base + (size_t)(q0 + nt * 16 + c) * 64 + kt * 32 + g * 8);

  s16x8 onesf;
  #pragma unroll
  for (int j = 0; j < 8; ++j) onesf[j] = (short)0x3F80;   // bf16 1.0

  f32x4 o[4][2];
  f32x4 ol[2];                              // l accumulators (all 4 regs equal)
  #pragma unroll
  for (int i = 0; i < 4; ++i) { o[i][0] = f32x4{0.f,0.f,0.f,0.f}; o[i][1] = f32x4{0.f,0.f,0.f,0.f}; }
  ol[0] = f32x4{0.f,0.f,0.f,0.f};
  ol[1] = f32x4{0.f,0.f,0.f,0.f};

  const int row1 = t >> 3, ch1 = t & 7;
  char* Pw = (char*)&Ps[w][0];
  char* Kb = (char*)Ks;
  char* Vb = (char*)Vs;

  // prologue: load tile 0 K and V^T into regs
  s16x8 kreg[2], vreg[2];
  #pragma unroll
  for (int j = 0; j < 2; ++j) {
    const int row = row1 + 32 * j;
    kreg[j] = *(const s16x8*)(Kg + base + (size_t)row * 64 + ch1 * 8);
    vreg[j] = *(const s16x8*)(Vtg + base + (size_t)row * 2048 + ch1 * 8);
  }

  for (int it = 0; it < 32; ++it) {
    const int kv0 = it * 64;
    #pragma unroll
    for (int j = 0; j < 2; ++j) {
      const int row = row1 + 32 * j;
      *(s16x8*)(Kb + swz(row, ch1 * 16)) = kreg[j];
      *(s16x8*)(Vb + swz(row, ch1 * 16)) = vreg[j];
    }
    __syncthreads();
    if (it != 31) {
      const int kv0n = kv0 + 64;
      #pragma unroll
      for (int j = 0; j < 2; ++j) {
        const int row = row1 + 32 * j;
        kreg[j] = *(const s16x8*)(Kg + base + (size_t)(kv0n + row) * 64 + ch1 * 8);
        vreg[j] = *(const s16x8*)(Vtg + base + (size_t)row * 2048 + kv0n + ch1 * 8);
      }
    }

    // ---- S^T = K * Q^T ----
    f32x4 st[4][2];
    __builtin_amdgcn_s_setprio(1);
    #pragma unroll
    for (int mt = 0; mt < 4; ++mt) {
      const int kr = mt * 16 + c;
      const s16x8 k0 = *(const s16x8*)(Kb + swz(kr, g * 16));
      const s16x8 k1 = *(const s16x8*)(Kb + swz(kr, 64 + g * 16));
      #pragma unroll
      for (int nt = 0; nt < 2; ++nt) {
        f32x4 z = {0.f, 0.f, 0.f, 0.f};
        z = MFMA16(k0, qf[nt][0], z);
        z = MFMA16(k1, qf[nt][1], z);
        st[mt][nt] = z;
      }
    }
    __builtin_amdgcn_s_setprio(0);

    // ---- P = exp2(S) (no max needed: range-safe), pack + write to per-wave LDS ----
    #pragma unroll
    for (int nt = 0; nt < 2; ++nt) {
      const int q32 = nt * 16 + c;
      #pragma unroll
      for (int mt = 0; mt < 4; ++mt) {
        const float p0 = exp2f(st[mt][nt][0]);
        const float p1 = exp2f(st[mt][nt][1]);
        const float p2 = exp2f(st[mt][nt][2]);
        const float p3 = exp2f(st[mt][nt][3]);
        u32x2 pv;
        pv[0] = cvt_pk_bf16(p0, p1);
        pv[1] = cvt_pk_bf16(p2, p3);
        *(u32x2*)(Pw + swz(q32, mt * 32 + g * 8)) = pv;
      }
    }
    asm volatile("s_waitcnt lgkmcnt(0)" ::: "memory");   // same-wave LDS RAW (both nt)

    // ---- PV: O^T += V^T * P^T ; l += ones * P^T (V/P fragments shared) ----
    __builtin_amdgcn_s_setprio(1);
    #pragma unroll
    for (int kkb = 0; kkb < 2; ++kkb) {
      const s16x8 pb0 = *(const s16x8*)(Pw + swz(c,      kkb * 64 + g * 16));
      const s16x8 pb1 = *(const s16x8*)(Pw + swz(16 + c, kkb * 64 + g * 16));
      ol[0] = MFMA16(onesf, pb0, ol[0]);
      ol[1] = MFMA16(onesf, pb1, ol[1]);
      #pragma unroll
      for (int dt = 0; dt < 4; ++dt) {
        const s16x8 vfr = *(const s16x8*)(Vb + swz(dt * 16 + c, kkb * 64 + g * 16));
        o[dt][0] = MFMA16(vfr, pb0, o[dt][0]);
        o[dt][1] = MFMA16(vfr, pb1, o[dt][1]);
      }
    }
    __builtin_amdgcn_s_setprio(0);
    __syncthreads();
  }

  // ---- epilogue: O^T/l -> attn_out bf16 (B,S,E) ----
  const int b = bh >> 4, h = bh & 15;
  #pragma unroll
  for (int nt = 0; nt < 2; ++nt) {
    const float inv = 1.0f / ol[nt][0];
    const int token = q0 + nt * 16 + c;
    u16* orow = Og + ((size_t)(b * 2048 + token)) * 1024 + h * 64;
    #pragma unroll
    for (int dt = 0; dt < 4; ++dt) {
      u32x2 pv;
      pv[0] = cvt_pk_bf16(o[dt][nt][0] * inv, o[dt][nt][1] * inv);
      pv[1] = cvt_pk_bf16(o[dt][nt][2] * inv, o[dt][nt][3] * inv);
      *(u32x2*)(orow + dt * 16 + g * 4) = pv;
    }
  }
}

// ---------------- launcher ----------------
extern "C" void kernel_launch(void* const* d_in, const int* in_sizes, int n_in,
                              void* d_out, int out_size, void* d_ws, size_t ws_size,
                              hipStream_t stream) {
  (void)in_sizes; (void)n_in; (void)out_size; (void)ws_size;
  const float* query   = (const float*)d_in[0];
  const float* key     = (const float*)d_in[1];
  const float* value   = (const float*)d_in[2];
  const float* wq      = (const float*)d_in[3];
  const float* bq      = (const float*)d_in[4];
  const float* wk      = (const float*)d_in[5];
  const float* bk      = (const float*)d_in[6];
  const float* wv      = (const float*)d_in[7];
  const float* bv      = (const float*)d_in[8];
  const float* wo      = (const float*)d_in[9];
  const float* bo      = (const float*)d_in[10];
  const float* q_theta = (const float*)d_in[11];
  const float* q_phi   = (const float*)d_in[12];
  const float* q_preW  = (const float*)d_in[13];
  const float* q_preb  = (const float*)d_in[14];
  const float* q_postW = (const float*)d_in[15];
  const float* q_postb = (const float*)d_in[16];
  const float* k_theta = (const float*)d_in[17];
  const float* k_phi   = (const float*)d_in[18];
  const float* k_preW  = (const float*)d_in[19];
  const float* k_preb  = (const float*)d_in[20];
  const float* k_postW = (const float*)d_in[21];
  const float* k_postb = (const float*)d_in[22];

  char* ws = (char*)d_ws;
  const size_t ACT = (size_t)8192 * 1024 * 2;   // one bf16 activation tensor (16 MB)
  u16* Qt  = (u16*)(ws + 0 * ACT);              // (B,H,S,64) bf16
  u16* Kt  = (u16*)(ws + 1 * ACT);              // (B,H,S,64) bf16
  u16* VtT = (u16*)(ws + 2 * ACT);              // (B,H,64,S) bf16  == V^T per (b,h)
  u16* AO  = (u16*)(ws + 3 * ACT);              // attn out, (B,S,E) bf16
  char* wb = ws + 4 * ACT;
  const size_t WSZ = (size_t)1024 * 1024 * 2;
  u16* Wqp = (u16*)(wb);
  u16* Wkp = (u16*)(wb + WSZ);
  u16* Wvb = (u16*)(wb + 2 * WSZ);
  u16* Wob = (u16*)(wb + 3 * WSZ);
  float* bqp = (float*)(wb + 4 * WSZ);
  float* bkp = (float*)(wb + 4 * WSZ + 4096);
  float* Aq  = (float*)(wb + 4 * WSZ + 8192);
  float* Ak  = (float*)(wb + 4 * WSZ + 8192 + 16384);
  float* cq  = (float*)(wb + 4 * WSZ + 8192 + 32768);
  float* ck  = (float*)(wb + 4 * WSZ + 8192 + 32768 + 256);

  cvt_f32_bf16<<<1024, 256, 0, stream>>>(wv, Wvb, 1048576);
  cvt_f32_bf16<<<1024, 256, 0, stream>>>(wo, Wob, 1048576);
  build_quantum<<<1, 256, 0, stream>>>(q_theta, q_phi, q_preW, q_preb, q_postW, q_postb, Aq, cq);
  build_quantum<<<1, 256, 0, stream>>>(k_theta, k_phi, k_preW, k_preb, k_postW, k_postb, Ak, ck);
  // Q scale = 1/sqrt(64) * log2(e): scores emerge in exp2 domain
  fold_weight<<<dim3(16, 16), 256, 0, stream>>>(Aq, cq, wq, bq, Wqp, bqp, 0.18033688f);
  fold_weight<<<dim3(16, 16), 256, 0, stream>>>(Ak, ck, wk, bk, Wkp, bkp, 1.0f);

  gemm_rs<1, 0><<<dim3(64, 8), 256, 0, stream>>>(query, Wqp, bqp, Qt,  nullptr, 8192, 1024, 1024);
  gemm_rs<1, 0><<<dim3(64, 8), 256, 0, stream>>>(key,   Wkp, bkp, Kt,  nullptr, 8192, 1024, 1024);
  gemm_rs<1, 2><<<dim3(64, 8), 256, 0, stream>>>(value, Wvb, bv,  VtT, nullptr, 8192, 1024, 1024);

  attn_fwd<<<1024, 256, 0, stream>>>(Qt, Kt, VtT, AO);

  gemm_rs<0, 1><<<dim3(64, 8), 256, 0, stream>>>(AO, Wob, bo, nullptr, (float*)d_out, 8192, 1024, 1024);
}

// Round 12
// 246.294 us; speedup vs baseline: 1.3848x; 1.2146x over previous
//
#include <hip/hip_runtime.h>
#include <cstdint>

typedef unsigned short u16;
typedef __attribute__((ext_vector_type(4))) float f32x4;
typedef __attribute__((ext_vector_type(8))) short s16x8;
typedef __attribute__((ext_vector_type(2))) unsigned int u32x2;
typedef __attribute__((ext_vector_type(4))) unsigned int u32x4;
typedef __attribute__((ext_vector_type(4))) unsigned short u16x4;

#define MFMA16(a,b,c) __builtin_amdgcn_mfma_f32_16x16x32_bf16((a),(b),(c),0,0,0)

__device__ __forceinline__ u16 f2bf(float x) {
  unsigned u = __builtin_bit_cast(unsigned, x);
  unsigned r = (u + 0x7fffu + ((u >> 16) & 1u)) >> 16;   // RNE
  return (u16)r;
}
__device__ __forceinline__ unsigned cvt_pk_bf16(float lo, float hi) {
  unsigned r;
  asm volatile("v_cvt_pk_bf16_f32 %0, %1, %2" : "=v"(r) : "v"(lo), "v"(hi));
  return r;
}
// byte offset into a [rows][64]-u16 LDS tile, XOR-swizzled (G4 pattern)
__device__ __forceinline__ int swz(int row, int colb) {
  return (row * 128 + colb) ^ ((row & 7) << 4);
}
// async global->LDS, 16B/lane; LDS dest = wave-uniform base + lane*16
__device__ __forceinline__ void glds16(const u16* g, u16* l) {
  __builtin_amdgcn_global_load_lds(
      (const __attribute__((address_space(1))) void*)g,
      (__attribute__((address_space(3))) void*)l, 16, 0, 0);
}

// ---------------- fp32 -> bf16 convert (wv + wo in one dispatch) ----------------
__global__ void cvt_f32_bf16_2(const float* __restrict__ inA, u16* __restrict__ outA,
                               const float* __restrict__ inB, u16* __restrict__ outB, int n) {
  const float* in = blockIdx.y ? inB : inA;
  u16* out = blockIdx.y ? outB : outA;
  const int i = (blockIdx.x * 256 + threadIdx.x) * 4;
  if (i + 3 < n) {
    const float4 v = *(const float4*)(in + i);
    u32x2 o2;
    o2[0] = cvt_pk_bf16(v.x, v.y);
    o2[1] = cvt_pk_bf16(v.z, v.w);
    *(u32x2*)(out + i) = o2;
  }
}

// ---------------- quantum layer -> affine map A'(64x64), c(64); q and k in one dispatch --------
// R = Kronecker product of 6 commuting 2x2 stage matrices M_i = [[c,-s],[s*cp,c*cp]].
__global__ __launch_bounds__(256) void build_quantum2(
    const float* __restrict__ thq, const float* __restrict__ phq,
    const float* __restrict__ preWq, const float* __restrict__ prebq,
    const float* __restrict__ postWq, const float* __restrict__ postbq,
    float* __restrict__ Aoutq, float* __restrict__ coutq,
    const float* __restrict__ thk, const float* __restrict__ phk,
    const float* __restrict__ preWk, const float* __restrict__ prebk,
    const float* __restrict__ postWk, const float* __restrict__ postbk,
    float* __restrict__ Aoutk, float* __restrict__ coutk) {
  const int zq = blockIdx.x == 0;
  const float* theta = zq ? thq : thk;
  const float* phi   = zq ? phq : phk;
  const float* preW  = zq ? preWq : preWk;
  const float* preb  = zq ? prebq : prebk;
  const float* postW = zq ? postWq : postWk;
  const float* postb = zq ? postbq : postbk;
  float* Aout  = zq ? Aoutq : Aoutk;
  float* cout_ = zq ? coutq : coutk;

  __shared__ float R[64][65];
  __shared__ float W[64][65];
  __shared__ float T[64][65];
  __shared__ float rbv[64];
  const int t = threadIdx.x;

  float m00[6], m01[6], m10[6], m11[6];
  #pragma unroll
  for (int i = 0; i < 6; ++i) {
    const float cth = cosf(theta[i]), sth = sinf(theta[i]), cph = cosf(phi[i]);
    m00[i] = cth; m01[i] = -sth; m10[i] = sth * cph; m11[i] = cth * cph;
  }
  for (int ii = t; ii < 4096; ii += 256) {
    const int r = ii >> 6, cc = ii & 63;
    float p = 1.f;
    #pragma unroll
    for (int i = 0; i < 6; ++i) {
      const int rb_ = (r >> i) & 1, cb = (cc >> i) & 1;
      p *= rb_ ? (cb ? m11[i] : m10[i]) : (cb ? m01[i] : m00[i]);
    }
    R[r][cc] = p;
    W[r][cc] = preW[ii];
  }
  __syncthreads();
  for (int ii = t; ii < 4096; ii += 256) {
    const int d = ii >> 6, j = ii & 63;
    float acc = 0.f;
    #pragma unroll
    for (int e = 0; e < 64; ++e) acc += R[d][e] * W[e][j];
    T[d][j] = acc;
  }
  if (t < 64) {
    float acc = 0.f;
    #pragma unroll
    for (int e = 0; e < 64; ++e) acc += R[t][e] * preb[e];
    rbv[t] = acc;
  }
  __syncthreads();
  for (int ii = t; ii < 4096; ii += 256) W[ii >> 6][ii & 63] = postW[ii];
  __syncthreads();
  for (int ii = t; ii < 4096; ii += 256) {
    const int d = ii >> 6, j = ii & 63;
    float acc = (d == j) ? 1.f : 0.f;
    #pragma unroll
    for (int e = 0; e < 64; ++e) acc += W[d][e] * T[e][j];
    Aout[ii] = acc;
  }
  if (t < 64) {
    float acc = postb[t];
    #pragma unroll
    for (int e = 0; e < 64; ++e) acc += W[t][e] * rbv[e];
    cout_[t] = acc;
  }
}

// ---------------- fold A' into projection weight (per head, block-diag); q and k (z) ----------
__global__ __launch_bounds__(256) void fold_weight2(
    const float* __restrict__ Aq, const float* __restrict__ cq,
    const float* __restrict__ wq, const float* __restrict__ bq,
    u16* __restrict__ Wqp, float* __restrict__ bqp,
    const float* __restrict__ Ak, const float* __restrict__ ck,
    const float* __restrict__ wk, const float* __restrict__ bk,
    u16* __restrict__ Wkp, float* __restrict__ bkp) {
  const int zq = blockIdx.z == 0;
  const float* Ap   = zq ? Aq : Ak;
  const float* cvec = zq ? cq : ck;
  const float* W    = zq ? wq : wk;
  const float* bin  = zq ? bq : bk;
  u16* Wout   = zq ? Wqp : Wkp;
  float* bout = zq ? bqp : bkp;
  const float scale = zq ? 0.18033688f : 1.0f;   // q: 1/sqrt(64)*log2(e)

  __shared__ float sW[64][64];
  __shared__ float sA[64][64];
  const int h = blockIdx.y, k0 = blockIdx.x * 64;
  const int t = threadIdx.x;
  for (int ii = t; ii < 4096; ii += 256) {
    const int e = ii >> 6, kk = ii & 63;
    sW[e][kk] = W[(size_t)(h * 64 + e) * 1024 + k0 + kk];
    sA[e][kk] = Ap[ii];
  }
  __syncthreads();
  for (int ii = t; ii < 4096; ii += 256) {
    const int d = ii >> 6, kk = ii & 63;
    float acc = 0.f;
    #pragma unroll
    for (int e = 0; e < 64; ++e) acc += sA[d][e] * sW[e][kk];
    Wout[(size_t)(h * 64 + d) * 1024 + k0 + kk] = f2bf(acc * scale);
  }
  if (blockIdx.x == 0 && t < 64) {
    const int d = t;
    float acc = cvec[d];
    for (int e = 0; e < 64; ++e) acc += sA[d][e] * bin[h * 64 + e];
    bout[h * 64 + d] = acc * scale;
  }
}

// ---------------- fused Q/K/V projection: 3 GEMMs in one dispatch (z picks source) ------------
// Body identical to r11 gemm_rs<1,MODE>: 128x128 tile, BK=64, B via global_load_lds w16
// double-buffered XOR-swizzled; A f32 reg-staged + cvt. z=0,1: mode-0 out; z=2: V^T out.
__global__ __launch_bounds__(256, 2) void qkv_proj(
    const float* __restrict__ qsrc, const float* __restrict__ ksrc, const float* __restrict__ vsrc,
    const u16* __restrict__ Wq, const u16* __restrict__ Wk, const u16* __restrict__ Wv,
    const float* __restrict__ bq, const float* __restrict__ bk, const float* __restrict__ bv,
    u16* __restrict__ Qt, u16* __restrict__ Kt, u16* __restrict__ VtT) {
  const int z = blockIdx.z;
  const float* Af = (z == 0) ? qsrc : (z == 1) ? ksrc : vsrc;
  const u16* Bw   = (z == 0) ? Wq : (z == 1) ? Wk : Wv;
  const float* bias = (z == 0) ? bq : (z == 1) ? bk : bv;
  u16* outB = (z == 0) ? Qt : (z == 1) ? Kt : VtT;
  const int K = 1024;

  __shared__ u16 AsBuf[9216];                  // [128][72]
  __shared__ u16 Bs[2][8192];                  // [2][128][64] glds, swizzled
  const int t = threadIdx.x;
  const int l = t & 63, w = t >> 6;
  const int g = l >> 4, c = l & 15;
  const int wr = w >> 1, wc = w & 1;
  const int m0 = blockIdx.x * 128, n0 = blockIdx.y * 128;

  const int lrow8 = l >> 3;
  const int gcolsw = ((l & 7) ^ lrow8) * 8;    // pre-swizzled source k-offset (elems)
  const int lbase = w * 512;

  auto glds_tile = [&](const u16* src, u16* ldsbuf, int rbase, int kk) {
    #pragma unroll
    for (int i = 0; i < 4; ++i) {
      const int grow = i * 32 + w * 8 + lrow8;
      glds16(src + (size_t)(rbase + grow) * K + kk + gcolsw, ldsbuf + i * 2048 + lbase);
    }
  };

  const int rowA32 = t >> 3, colA32 = (t & 7) * 8;
  float4 fa[4][2];
  auto issue_A = [&](int kk) {
    #pragma unroll
    for (int i2 = 0; i2 < 4; ++i2) {
      const float* p = Af + (size_t)(m0 + rowA32 + i2 * 32) * K + kk + colA32;
      fa[i2][0] = *(const float4*)p;
      fa[i2][1] = *(const float4*)(p + 4);
    }
  };

  f32x4 acc[4][4];
  #pragma unroll
  for (int i = 0; i < 4; ++i)
    #pragma unroll
    for (int j = 0; j < 4; ++j) acc[i][j] = f32x4{0.f, 0.f, 0.f, 0.f};

  issue_A(0);
  glds_tile(Bw, Bs[0], n0, 0);

  int cur = 0;
  for (int kk = 0; kk < K; kk += 64) {
    #pragma unroll
    for (int i2 = 0; i2 < 4; ++i2) {
      u32x4 o4;
      o4[0] = cvt_pk_bf16(fa[i2][0].x, fa[i2][0].y);
      o4[1] = cvt_pk_bf16(fa[i2][0].z, fa[i2][0].w);
      o4[2] = cvt_pk_bf16(fa[i2][1].x, fa[i2][1].y);
      o4[3] = cvt_pk_bf16(fa[i2][1].z, fa[i2][1].w);
      *(u32x4*)&AsBuf[(rowA32 + i2 * 32) * 72 + colA32] = o4;
    }
    __syncthreads();                      // A visible; glds(kk) drained
    const int nk = kk + 64;
    if (nk < K) {
      glds_tile(Bw, Bs[cur ^ 1], n0, nk);
      issue_A(nk);
    }

    s16x8 af[4][2], bfr[4][2];
    #pragma unroll
    for (int mi = 0; mi < 4; ++mi)
      #pragma unroll
      for (int kt = 0; kt < 2; ++kt)
        af[mi][kt] = *(const s16x8*)&AsBuf[(wr * 64 + mi * 16 + c) * 72 + kt * 32 + g * 8];
    {
      const char* Bb = (const char*)Bs[cur];
      #pragma unroll
      for (int ni = 0; ni < 4; ++ni) {
        const int rr = wc * 64 + ni * 16 + c;
        #pragma unroll
        for (int kt = 0; kt < 2; ++kt)
          bfr[ni][kt] = *(const s16x8*)(Bb + rr * 128 + (((kt * 4 + g) ^ (c & 7)) << 4));
      }
    }
    #pragma unroll
    for (int kt = 0; kt < 2; ++kt)
      #pragma unroll
      for (int mi = 0; mi < 4; ++mi)
        #pragma unroll
        for (int ni = 0; ni < 4; ++ni)
          acc[mi][ni] = MFMA16(af[mi][kt], bfr[ni][kt], acc[mi][ni]);
    __syncthreads();
    cur ^= 1;
  }

  #pragma unroll
  for (int ni = 0; ni < 4; ++ni) {
    const int n = n0 + wc * 64 + ni * 16 + c;
    const float bb = bias[n];
    #pragma unroll
    for (int mi = 0; mi < 4; ++mi) {
      const int mb = m0 + wr * 64 + mi * 16 + g * 4;
      if (z == 2) {
        // V^T output: (B,H,64,S)
        const int b = mb >> 11, sb = mb & 2047, h = n >> 6, d = n & 63;
        u16x4 pk;
        #pragma unroll
        for (int r = 0; r < 4; ++r) pk[r] = f2bf(acc[mi][ni][r] + bb);
        *(u16x4*)(outB + ((size_t)(b * 16 + h) * 64 + d) * 2048 + sb) = pk;
      } else {
        #pragma unroll
        for (int r = 0; r < 4; ++r) {
          const int m = mb + r;
          const int b = m >> 11, s = m & 2047, h = n >> 6, d = n & 63;
          outB[((size_t)((b * 16 + h) * 2048 + s)) * 64 + d] = f2bf(acc[mi][ni][r] + bb);
        }
      }
    }
  }
}

// ---------------- output-projection GEMM (bf16 A via glds, f32 out) ----------------
__global__ __launch_bounds__(256, 2) void gemm_out(
    const u16* __restrict__ Ab, const u16* __restrict__ Bw,
    const float* __restrict__ bias, float* __restrict__ outF, int M, int N, int K) {
  __shared__ u16 As[2][8192];
  __shared__ u16 Bs[2][8192];
  const int t = threadIdx.x;
  const int l = t & 63, w = t >> 6;
  const int g = l >> 4, c = l & 15;
  const int wr = w >> 1, wc = w & 1;
  const int m0 = blockIdx.x * 128, n0 = blockIdx.y * 128;

  const int lrow8 = l >> 3;
  const int gcolsw = ((l & 7) ^ lrow8) * 8;
  const int lbase = w * 512;

  auto glds_tile = [&](const u16* src, u16* ldsbuf, int rbase, int kk) {
    #pragma unroll
    for (int i = 0; i < 4; ++i) {
      const int grow = i * 32 + w * 8 + lrow8;
      glds16(src + (size_t)(rbase + grow) * K + kk + gcolsw, ldsbuf + i * 2048 + lbase);
    }
  };

  f32x4 acc[4][4];
  #pragma unroll
  for (int i = 0; i < 4; ++i)
    #pragma unroll
    for (int j = 0; j < 4; ++j) acc[i][j] = f32x4{0.f, 0.f, 0.f, 0.f};

  glds_tile(Ab, As[0], m0, 0);
  glds_tile(Bw, Bs[0], n0, 0);

  int cur = 0;
  for (int kk = 0; kk < K; kk += 64) {
    __syncthreads();
    const int nk = kk + 64;
    if (nk < K) {
      glds_tile(Ab, As[cur ^ 1], m0, nk);
      glds_tile(Bw, Bs[cur ^ 1], n0, nk);
    }
    s16x8 af[4][2], bfr[4][2];
    {
      const char* Ab2 = (const char*)As[cur];
      #pragma unroll
      for (int mi = 0; mi < 4; ++mi) {
        const int ar = wr * 64 + mi * 16 + c;
        #pragma unroll
        for (int kt = 0; kt < 2; ++kt)
          af[mi][kt] = *(const s16x8*)(Ab2 + ar * 128 + (((kt * 4 + g) ^ (c & 7)) << 4));
      }
      const char* Bb = (const char*)Bs[cur];
      #pragma unroll
      for (int ni = 0; ni < 4; ++ni) {
        const int rr = wc * 64 + ni * 16 + c;
        #pragma unroll
        for (int kt = 0; kt < 2; ++kt)
          bfr[ni][kt] = *(const s16x8*)(Bb + rr * 128 + (((kt * 4 + g) ^ (c & 7)) << 4));
      }
    }
    #pragma unroll
    for (int kt = 0; kt < 2; ++kt)
      #pragma unroll
      for (int mi = 0; mi < 4; ++mi)
        #pragma unroll
        for (int ni = 0; ni < 4; ++ni)
          acc[mi][ni] = MFMA16(af[mi][kt], bfr[ni][kt], acc[mi][ni]);
    __syncthreads();
    cur ^= 1;
  }

  #pragma unroll
  for (int ni = 0; ni < 4; ++ni) {
    const int n = n0 + wc * 64 + ni * 16 + c;
    const float bb = bias[n];
    #pragma unroll
    for (int mi = 0; mi < 4; ++mi) {
      const int mb = m0 + wr * 64 + mi * 16 + g * 4;
      #pragma unroll
      for (int r = 0; r < 4; ++r)
        outF[(size_t)(mb + r) * N + n] = acc[mi][ni][r] + bb;
    }
  }
}

// ---------------- flash attention (r11 config — best known) ----------------
__global__ __launch_bounds__(256, 2) void attn_fwd(
    const u16* __restrict__ Qg, const u16* __restrict__ Kg,
    const u16* __restrict__ Vtg, u16* __restrict__ Og) {
  __shared__ u16 Ks[64 * 64];
  __shared__ u16 Vs[64 * 64];
  __shared__ u16 Ps[4][32 * 64];
  const int t = threadIdx.x;
  const int l = t & 63, w = t >> 6;
  const int g = l >> 4, c = l & 15;
  const int bid = blockIdx.x;
  const int xcd = bid & 7, kk_ = bid >> 3;
  const int bh = ((kk_ >> 4) << 3) + xcd;   // 0..63
  const int qx = kk_ & 15;                  // 0..15
  const size_t base = (size_t)bh * (2048 * 64);
  const int q0 = qx * 128 + w * 32;

  s16x8 qf[2][2];
  #pragma unroll
  for (int nt = 0; nt < 2; ++nt)
    #pragma unroll
    for (int kt = 0; kt < 2; ++kt)
      qf[nt][kt] = *(const s16x8*)(Qg + base + (size_t)(q0 + nt * 16 + c) * 64 + kt * 32 + g * 8);

  s16x8 onesf;
  #pragma unroll
  for (int j = 0; j < 8; ++j) onesf[j] = (short)0x3F80;   // bf16 1.0

  f32x4 o[4][2];
  f32x4 ol[2];
  #pragma unroll
  for (int i = 0; i < 4; ++i) { o[i][0] = f32x4{0.f,0.f,0.f,0.f}; o[i][1] = f32x4{0.f,0.f,0.f,0.f}; }
  ol[0] = f32x4{0.f,0.f,0.f,0.f};
  ol[1] = f32x4{0.f,0.f,0.f,0.f};

  const int row1 = t >> 3, ch1 = t & 7;
  char* Pw = (char*)&Ps[w][0];
  char* Kb = (char*)Ks;
  char* Vb = (char*)Vs;

  s16x8 kreg[2], vreg[2];
  #pragma unroll
  for (int j = 0; j < 2; ++j) {
    const int row = row1 + 32 * j;
    kreg[j] = *(const s16x8*)(Kg + base + (size_t)row * 64 + ch1 * 8);
    vreg[j] = *(const s16x8*)(Vtg + base + (size_t)row * 2048 + ch1 * 8);
  }

  for (int it = 0; it < 32; ++it) {
    const int kv0 = it * 64;
    #pragma unroll
    for (int j = 0; j < 2; ++j) {
      const int row = row1 + 32 * j;
      *(s16x8*)(Kb + swz(row, ch1 * 16)) = kreg[j];
      *(s16x8*)(Vb + swz(row, ch1 * 16)) = vreg[j];
    }
    __syncthreads();
    if (it != 31) {
      const int kv0n = kv0 + 64;
      #pragma unroll
      for (int j = 0; j < 2; ++j) {
        const int row = row1 + 32 * j;
        kreg[j] = *(const s16x8*)(Kg + base + (size_t)(kv0n + row) * 64 + ch1 * 8);
        vreg[j] = *(const s16x8*)(Vtg + base + (size_t)row * 2048 + kv0n + ch1 * 8);
      }
    }

    // ---- S^T = K * Q^T ----
    f32x4 st[4][2];
    __builtin_amdgcn_s_setprio(1);
    #pragma unroll
    for (int mt = 0; mt < 4; ++mt) {
      const int kr = mt * 16 + c;
      const s16x8 k0 = *(const s16x8*)(Kb + swz(kr, g * 16));
      const s16x8 k1 = *(const s16x8*)(Kb + swz(kr, 64 + g * 16));
      #pragma unroll
      for (int nt = 0; nt < 2; ++nt) {
        f32x4 z = {0.f, 0.f, 0.f, 0.f};
        z = MFMA16(k0, qf[nt][0], z);
        z = MFMA16(k1, qf[nt][1], z);
        st[mt][nt] = z;
      }
    }
    __builtin_amdgcn_s_setprio(0);

    // ---- P = exp2(S) (no max: range-safe), pack + write to per-wave LDS ----
    #pragma unroll
    for (int nt = 0; nt < 2; ++nt) {
      const int q32 = nt * 16 + c;
      #pragma unroll
      for (int mt = 0; mt < 4; ++mt) {
        const float p0 = exp2f(st[mt][nt][0]);
        const float p1 = exp2f(st[mt][nt][1]);
        const float p2 = exp2f(st[mt][nt][2]);
        const float p3 = exp2f(st[mt][nt][3]);
        u32x2 pv;
        pv[0] = cvt_pk_bf16(p0, p1);
        pv[1] = cvt_pk_bf16(p2, p3);
        *(u32x2*)(Pw + swz(q32, mt * 32 + g * 8)) = pv;
      }
    }
    asm volatile("s_waitcnt lgkmcnt(0)" ::: "memory");   // same-wave LDS RAW (both nt)

    // ---- PV: O^T += V^T * P^T ; l += ones * P^T ----
    __builtin_amdgcn_s_setprio(1);
    #pragma unroll
    for (int kkb = 0; kkb < 2; ++kkb) {
      const s16x8 pb0 = *(const s16x8*)(Pw + swz(c,      kkb * 64 + g * 16));
      const s16x8 pb1 = *(const s16x8*)(Pw + swz(16 + c, kkb * 64 + g * 16));
      ol[0] = MFMA16(onesf, pb0, ol[0]);
      ol[1] = MFMA16(onesf, pb1, ol[1]);
      #pragma unroll
      for (int dt = 0; dt < 4; ++dt) {
        const s16x8 vfr = *(const s16x8*)(Vb + swz(dt * 16 + c, kkb * 64 + g * 16));
        o[dt][0] = MFMA16(vfr, pb0, o[dt][0]);
        o[dt][1] = MFMA16(vfr, pb1, o[dt][1]);
      }
    }
    __builtin_amdgcn_s_setprio(0);
    __syncthreads();
  }

  // ---- epilogue: O^T/l -> attn_out bf16 (B,S,E) ----
  const int b = bh >> 4, h = bh & 15;
  #pragma unroll
  for (int nt = 0; nt < 2; ++nt) {
    const float inv = 1.0f / ol[nt][0];
    const int token = q0 + nt * 16 + c;
    u16* orow = Og + ((size_t)(b * 2048 + token)) * 1024 + h * 64;
    #pragma unroll
    for (int dt = 0; dt < 4; ++dt) {
      u32x2 pv;
      pv[0] = cvt_pk_bf16(o[dt][nt][0] * inv, o[dt][nt][1] * inv);
      pv[1] = cvt_pk_bf16(o[dt][nt][2] * inv, o[dt][nt][3] * inv);
      *(u32x2*)(orow + dt * 16 + g * 4) = pv;
    }
  }
}

// ---------------- launcher ----------------
extern "C" void kernel_launch(void* const* d_in, const int* in_sizes, int n_in,
                              void* d_out, int out_size, void* d_ws, size_t ws_size,
                              hipStream_t stream) {
  (void)in_sizes; (void)n_in; (void)out_size; (void)ws_size;
  const float* query   = (const float*)d_in[0];
  const float* key     = (const float*)d_in[1];
  const float* value   = (const float*)d_in[2];
  const float* wq      = (const float*)d_in[3];
  const float* bq      = (const float*)d_in[4];
  const float* wk      = (const float*)d_in[5];
  const float* bk      = (const float*)d_in[6];
  const float* wv      = (const float*)d_in[7];
  const float* bv      = (const float*)d_in[8];
  const float* wo      = (const float*)d_in[9];
  const float* bo      = (const float*)d_in[10];
  const float* q_theta = (const float*)d_in[11];
  const float* q_phi   = (const float*)d_in[12];
  const float* q_preW  = (const float*)d_in[13];
  const float* q_preb  = (const float*)d_in[14];
  const float* q_postW = (const float*)d_in[15];
  const float* q_postb = (const float*)d_in[16];
  const float* k_theta = (const float*)d_in[17];
  const float* k_phi   = (const float*)d_in[18];
  const float* k_preW  = (const float*)d_in[19];
  const float* k_preb  = (const float*)d_in[20];
  const float* k_postW = (const float*)d_in[21];
  const float* k_postb = (const float*)d_in[22];

  char* ws = (char*)d_ws;
  const size_t ACT = (size_t)8192 * 1024 * 2;   // one bf16 activation tensor (16 MB)
  u16* Qt  = (u16*)(ws + 0 * ACT);              // (B,H,S,64) bf16
  u16* Kt  = (u16*)(ws + 1 * ACT);              // (B,H,S,64) bf16
  u16* VtT = (u16*)(ws + 2 * ACT);              // (B,H,64,S) bf16  == V^T per (b,h)
  u16* AO  = (u16*)(ws + 3 * ACT);              // attn out, (B,S,E) bf16
  char* wb = ws + 4 * ACT;
  const size_t WSZ = (size_t)1024 * 1024 * 2;
  u16* Wqp = (u16*)(wb);
  u16* Wkp = (u16*)(wb + WSZ);
  u16* Wvb = (u16*)(wb + 2 * WSZ);
  u16* Wob = (u16*)(wb + 3 * WSZ);
  float* bqp = (float*)(wb + 4 * WSZ);
  float* bkp = (float*)(wb + 4 * WSZ + 4096);
  float* Aq  = (float*)(wb + 4 * WSZ + 8192);
  float* Ak  = (float*)(wb + 4 * WSZ + 8192 + 16384);
  float* cq  = (float*)(wb + 4 * WSZ + 8192 + 32768);
  float* ck  = (float*)(wb + 4 * WSZ + 8192 + 32768 + 256);

  cvt_f32_bf16_2<<<dim3(1024, 2), 256, 0, stream>>>(wv, Wvb, wo, Wob, 1048576);
  build_quantum2<<<2, 256, 0, stream>>>(
      q_theta, q_phi, q_preW, q_preb, q_postW, q_postb, Aq, cq,
      k_theta, k_phi, k_preW, k_preb, k_postW, k_postb, Ak, ck);
  fold_weight2<<<dim3(16, 16, 2), 256, 0, stream>>>(
      Aq, cq, wq, bq, Wqp, bqp, Ak, ck, wk, bk, Wkp, bkp);

  qkv_proj<<<dim3(64, 8, 3), 256, 0, stream>>>(
      query, key, value, Wqp, Wkp, Wvb, bqp, bkp, bv, Qt, Kt, VtT);

  attn_fwd<<<1024, 256, 0, stream>>>(Qt, Kt, VtT, AO);

  gemm_out<<<dim3(64, 8), 256, 0, stream>>>(AO, Wob, bo, (float*)d_out, 8192, 1024, 1024);
}